// Round 11
// baseline (127.550 us; speedup 1.0000x reference)
//
#include <hip/hip_runtime.h>

// SeqAdder: y[b,l], c_final[b] from a sequential per-digit MLP adder scan.
// Speculative chunked scan: carry recurrence is contracting; each chunk
// reconstructs its incoming carry with a WARM=48 warmup from c=0.5
// (absmax pinned at bf16 floor 1.95e-3 through R1-R4/R8/R9).
// R11 = R8 numerics + ONE structural change: coalesced loads via LDS.
//   Diagnosis: each lane streams its own 4KB-strided row, so every
//   global_load_dwordx4 scatters to 64 distinct cache lines -> the CU
//   vector-memory pipe is the shared cap (VALUBusy stuck 55-66% at both
//   2 and 4 waves/SIMD; R10's 1-wave ILP2 dropped to 42%).
//   Fix: wave cooperatively loads a [64 rows x 16 floats] tile (each
//   instruction = 16 consecutive-row 64B segments = 16 lines, fully
//   consumed) into regs AT GROUP TOP (T14 issue-early), computes the
//   current group from LDS, then ds_writes the regs (write-late; HBM/L2
//   latency hides under ~3400cy of compute). Lanes read their own row
//   from LDS (stride 20 floats -> banks spread). Single-wave block: no
//   barriers, DS ops in-order. LDS 10KB/block, 8 blocks/CU needed, 16 fit.

#define HIDDEN 16
constexpr int Bn = 4096;
constexpr int Ln = 4096;
constexpr int CHUNK = 128;           // steps written per thread
constexpr int WARM = 48;             // warmup steps (carry only)
constexpr int NCHUNK = Ln / CHUNK;   // 32
constexpr int GRAN = 16;             // floats per tile row (64B)
constexpr int WG = WARM / GRAN;      // 3 warm tiles
constexpr int MG = CHUNK / GRAN;     // 8 main tiles
constexpr int LSTR = 20;             // LDS row stride in floats (80B, 16B-mult)

__device__ __forceinline__ float fast_exp2(float x) {
#if __has_builtin(__builtin_amdgcn_exp2f)
  return __builtin_amdgcn_exp2f(x);
#else
  return exp2f(x);
#endif
}
__device__ __forceinline__ float fast_rcp(float x) {
#if __has_builtin(__builtin_amdgcn_rcpf)
  return __builtin_amdgcn_rcpf(x);
#else
  return 1.0f / x;
#endif
}
// with z already scaled by -log2(e):  sigmoid = 1 / (1 + 2^z)
__device__ __forceinline__ float sigmoid_pre(float z) {
  return fast_rcp(1.0f + fast_exp2(z));
}

__global__ __launch_bounds__(64) void seq_adder_kernel(
    const float* __restrict__ x1, const float* __restrict__ x2,
    const float* __restrict__ W1, const float* __restrict__ b1,
    const float* __restrict__ W2, const float* __restrict__ b2,
    float* __restrict__ out) {
  const int l = threadIdx.x;
  const int rowbase = blockIdx.x * 64;
  const int row = rowbase + l;
  const int ci = blockIdx.y;

  constexpr float NLOG2E = -1.4426950408889634f;

  // Wave-uniform weights; unrolled constant-index loads -> SGPRs.
  float w1a[HIDDEN], w1b[HIDDEN], w1c[HIDDEN], bb1[HIDDEN];
  float w2s[HIDDEN], w2c[HIDDEN];
#pragma unroll
  for (int j = 0; j < HIDDEN; ++j) {
    w1a[j] = W1[j];                       // W1[0, j] (multiplies a)
    w1b[j] = W1[HIDDEN + j];              // W1[1, j] (multiplies b)
    w1c[j] = W1[2 * HIDDEN + j];          // W1[2, j] (multiplies carry)
    bb1[j] = b1[j];
    w2s[j] = W2[2 * j + 0] * NLOG2E;      // fold -log2(e) into layer 2
    w2c[j] = W2[2 * j + 1] * NLOG2E;
  }
  const float b2s = b2[0] * NLOG2E, b2c = b2[1] * NLOG2E;

  __shared__ float lds_a[64 * LSTR];
  __shared__ float lds_b[64 * LSTR];

  float* __restrict__ yo = out + (size_t)row * Ln;

  // Cooperative-load geometry: instruction i covers rows i*16+(l>>2),
  // each lane loads 16B at col (l&3)*4 of its sub-row.
  const int cr = l >> 2;
  const int cc = (l & 3) * 4;
  const float* ga = x1 + (size_t)(rowbase + cr) * Ln + cc;
  const float* gb = x2 + (size_t)(rowbase + cr) * Ln + cc;

  const int l0 = ci * CHUNK;
  float c;

  float4 va[4], vb[4];  // staging regs (in flight during compute)

#define LOAD_TILE(lb)                                                     \
  do {                                                                    \
    _Pragma("unroll") for (int i_ = 0; i_ < 4; ++i_) {                    \
      va[i_] = *reinterpret_cast<const float4*>(ga + (size_t)i_ * 16 * Ln \
                                                + (lb));                  \
      vb[i_] = *reinterpret_cast<const float4*>(gb + (size_t)i_ * 16 * Ln \
                                                + (lb));                  \
    }                                                                     \
  } while (0)

#define STORE_LDS()                                                          \
  do {                                                                       \
    _Pragma("unroll") for (int i_ = 0; i_ < 4; ++i_) {                       \
      *reinterpret_cast<float4*>(&lds_a[(i_ * 16 + cr) * LSTR + cc]) =       \
          va[i_];                                                            \
      *reinterpret_cast<float4*>(&lds_b[(i_ * 16 + cr) * LSTR + cc]) =       \
          vb[i_];                                                            \
    }                                                                        \
  } while (0)

#define READ_LDS(a4, b4)                                                    \
  do {                                                                      \
    _Pragma("unroll") for (int q_ = 0; q_ < 4; ++q_) {                      \
      (a4)[q_] =                                                            \
          *reinterpret_cast<const float4*>(&lds_a[l * LSTR + q_ * 4]);      \
      (b4)[q_] =                                                            \
          *reinterpret_cast<const float4*>(&lds_b[l * LSTR + q_ * 4]);      \
    }                                                                       \
  } while (0)

  if (ci == 0) {
    c = 0.0f;  // exact initial carry
    LOAD_TILE(l0);
  } else {
    c = 0.5f;  // neutral guess; contraction erases it over WARM steps
    const int w0 = l0 - WARM;
    LOAD_TILE(w0);
#pragma unroll 1
    for (int t = 0; t < WG; ++t) {
      STORE_LDS();                       // tile t -> LDS (waits vmcnt)
      float4 a4[4], b4[4];
      READ_LDS(a4, b4);                  // in-order after write
      LOAD_TILE(w0 + (t + 1) * GRAN);    // t==WG-1 loads main tile 0 (l0)
      const float* af = reinterpret_cast<const float*>(a4);
      const float* bf = reinterpret_cast<const float*>(b4);
#pragma unroll
      for (int u = 0; u < GRAN; ++u) {
        const float a = af[u];
        const float b = bf[u];
        float pre[HIDDEN];
#pragma unroll
        for (int j = 0; j < HIDDEN; ++j)
          pre[j] = fmaf(a, w1a[j], fmaf(b, w1b[j], bb1[j]));
        float zc0 = b2c, zc1 = 0.f, zc2 = 0.f, zc3 = 0.f;
#pragma unroll
        for (int j = 0; j < HIDDEN; j += 4) {
          float h0 = fmaxf(fmaf(c, w1c[j + 0], pre[j + 0]), 0.f);
          float h1 = fmaxf(fmaf(c, w1c[j + 1], pre[j + 1]), 0.f);
          float h2 = fmaxf(fmaf(c, w1c[j + 2], pre[j + 2]), 0.f);
          float h3 = fmaxf(fmaf(c, w1c[j + 3], pre[j + 3]), 0.f);
          zc0 = fmaf(h0, w2c[j + 0], zc0);
          zc1 = fmaf(h1, w2c[j + 1], zc1);
          zc2 = fmaf(h2, w2c[j + 2], zc2);
          zc3 = fmaf(h3, w2c[j + 3], zc3);
        }
        c = sigmoid_pre((zc0 + zc1) + (zc2 + zc3));
      }
    }
  }

  // Main: emit sum bits + advance carry.
#pragma unroll 1
  for (int g = 0; g < MG; ++g) {
    STORE_LDS();                         // tile g -> LDS
    float4 a4[4], b4[4], y4[4];
    READ_LDS(a4, b4);
    if (g + 1 < MG) LOAD_TILE(l0 + (g + 1) * GRAN);  // issue-early
    const float* af = reinterpret_cast<const float*>(a4);
    const float* bf = reinterpret_cast<const float*>(b4);
    float* yf = reinterpret_cast<float*>(y4);
#pragma unroll
    for (int u = 0; u < GRAN; ++u) {
      const float a = af[u];
      const float b = bf[u];
      float pre[HIDDEN];
#pragma unroll
      for (int j = 0; j < HIDDEN; ++j)
        pre[j] = fmaf(a, w1a[j], fmaf(b, w1b[j], bb1[j]));
      float zc0 = b2c, zc1 = 0.f, zc2 = 0.f, zc3 = 0.f;
      float zs0 = b2s, zs1 = 0.f;
#pragma unroll
      for (int j = 0; j < HIDDEN; j += 4) {
        float h0 = fmaxf(fmaf(c, w1c[j + 0], pre[j + 0]), 0.f);
        float h1 = fmaxf(fmaf(c, w1c[j + 1], pre[j + 1]), 0.f);
        float h2 = fmaxf(fmaf(c, w1c[j + 2], pre[j + 2]), 0.f);
        float h3 = fmaxf(fmaf(c, w1c[j + 3], pre[j + 3]), 0.f);
        zc0 = fmaf(h0, w2c[j + 0], zc0);
        zc1 = fmaf(h1, w2c[j + 1], zc1);
        zc2 = fmaf(h2, w2c[j + 2], zc2);
        zc3 = fmaf(h3, w2c[j + 3], zc3);
        // zs is off the carry chain; 2 accumulators is plenty
        zs0 = fmaf(h0, w2s[j + 0], fmaf(h1, w2s[j + 1], zs0));
        zs1 = fmaf(h2, w2s[j + 2], fmaf(h3, w2s[j + 3], zs1));
      }
      yf[u] = sigmoid_pre(zs0 + zs1);
      c = sigmoid_pre((zc0 + zc1) + (zc2 + zc3));
    }
#pragma unroll
    for (int q = 0; q < 4; ++q) {
      *reinterpret_cast<float4*>(yo + l0 + g * GRAN + 4 * q) = y4[q];
    }
  }

  // Last chunk owns the final carry output.
  if (ci == NCHUNK - 1) {
    out[(size_t)Bn * Ln + row] = c;
  }
}

extern "C" void kernel_launch(void* const* d_in, const int* in_sizes, int n_in,
                              void* d_out, int out_size, void* d_ws,
                              size_t ws_size, hipStream_t stream) {
  const float* x1 = (const float*)d_in[0];
  const float* x2 = (const float*)d_in[1];
  const float* W1 = (const float*)d_in[2];
  const float* b1 = (const float*)d_in[3];
  const float* W2 = (const float*)d_in[4];
  const float* b2 = (const float*)d_in[5];
  float* out = (float*)d_out;

  dim3 grid(Bn / 64, NCHUNK);
  seq_adder_kernel<<<grid, 64, 0, stream>>>(x1, x2, W1, b1, W2, b2, out);
}

// Round 12
// 83.419 us; speedup vs baseline: 1.5290x; 1.5290x over previous
//
#include <hip/hip_runtime.h>

// SeqAdder: y[b,l], c_final[b] from a sequential per-digit MLP adder scan.
// Speculative chunked scan: the carry recurrence is contracting, so each
// chunk reconstructs its incoming carry with a WARM-step warmup from c=0.5.
// Chunk 0 starts from the exact c0=0.
// Ledger: absmax pinned at bf16 floor (1.95e-3) for WARM=64 (R1-R4) and
// WARM=48 (R8/R9). WARM=48, 64B-aligned (R9's WARM=40 misalignment: +23MB).
// R12 = R8 EXACTLY + __launch_bounds__(64, 2).
//   Root cause found in R8-R11: plain launch_bounds(64) leaves the default
//   occupancy target (~8 waves/EU) => 64-VGPR budget. VGPR_Count was pinned
//   at 56-64 in EVERY round: the compiler sank group loads just-in-time
//   (R8), ignored keepalive hoist attempts (R9), and spilled staging arrays
//   to scratch (R11: WRITE_SIZE 75->246MB, the spill signature).
//   Grid is 2048 blocks = 8 waves/CU = 2 waves/EU anyway (occupancy ~17%
//   grid-capped), so min-2-waves/EU costs nothing and raises the VGPR cap
//   to 256: the compiler can hoist all 8 dwordx4 to group top itself.

#define HIDDEN 16
constexpr int Bn = 4096;
constexpr int Ln = 4096;
constexpr int CHUNK = 128;           // steps written per thread
constexpr int WARM = 48;             // speculative warmup steps (carry only)
constexpr int NCHUNK = Ln / CHUNK;   // 32
constexpr int GRAN = 16;             // floats register-buffered per group (64B)

__device__ __forceinline__ float fast_exp2(float x) {
#if __has_builtin(__builtin_amdgcn_exp2f)
  return __builtin_amdgcn_exp2f(x);
#else
  return exp2f(x);
#endif
}
__device__ __forceinline__ float fast_rcp(float x) {
#if __has_builtin(__builtin_amdgcn_rcpf)
  return __builtin_amdgcn_rcpf(x);
#else
  return 1.0f / x;
#endif
}
// with z already scaled by -log2(e):  sigmoid = 1 / (1 + 2^z)
__device__ __forceinline__ float sigmoid_pre(float z) {
  return fast_rcp(1.0f + fast_exp2(z));
}

__global__ __launch_bounds__(64, 2) void seq_adder_kernel(
    const float* __restrict__ x1, const float* __restrict__ x2,
    const float* __restrict__ W1, const float* __restrict__ b1,
    const float* __restrict__ W2, const float* __restrict__ b2,
    float* __restrict__ out) {
  const int row = blockIdx.x * 64 + threadIdx.x;
  const int ci = blockIdx.y;

  constexpr float NLOG2E = -1.4426950408889634f;

  // Wave-uniform weights; unrolled constant-index loads -> SGPRs.
  float w1a[HIDDEN], w1b[HIDDEN], w1c[HIDDEN], bb1[HIDDEN];
  float w2s[HIDDEN], w2c[HIDDEN];
#pragma unroll
  for (int j = 0; j < HIDDEN; ++j) {
    w1a[j] = W1[j];                       // W1[0, j] (multiplies a)
    w1b[j] = W1[HIDDEN + j];              // W1[1, j] (multiplies b)
    w1c[j] = W1[2 * HIDDEN + j];          // W1[2, j] (multiplies carry)
    bb1[j] = b1[j];
    w2s[j] = W2[2 * j + 0] * NLOG2E;      // fold -log2(e) into layer 2
    w2c[j] = W2[2 * j + 1] * NLOG2E;
  }
  const float b2s = b2[0] * NLOG2E, b2c = b2[1] * NLOG2E;

  const float* __restrict__ r1 = x1 + (size_t)row * Ln;
  const float* __restrict__ r2 = x2 + (size_t)row * Ln;
  float* __restrict__ yo = out + (size_t)row * Ln;

  const int l0 = ci * CHUNK;
  float c;

  if (ci == 0) {
    c = 0.0f;  // exact initial carry
  } else {
    c = 0.5f;  // neutral guess; contraction erases it over WARM steps
    for (int g = 0; g < WARM / GRAN; ++g) {
      const int lb = l0 - WARM + g * GRAN;
      float4 a4[GRAN / 4], b4[GRAN / 4];
#pragma unroll
      for (int q = 0; q < GRAN / 4; ++q) {
        a4[q] = *reinterpret_cast<const float4*>(r1 + lb + 4 * q);
        b4[q] = *reinterpret_cast<const float4*>(r2 + lb + 4 * q);
      }
      const float* af = reinterpret_cast<const float*>(a4);
      const float* bf = reinterpret_cast<const float*>(b4);
#pragma unroll
      for (int u = 0; u < GRAN; ++u) {
        const float a = af[u];
        const float b = bf[u];
        // off-chain: a,b-dependent preactivation (2 FMA each)
        float pre[HIDDEN];
#pragma unroll
        for (int j = 0; j < HIDDEN; ++j)
          pre[j] = fmaf(a, w1a[j], fmaf(b, w1b[j], bb1[j]));
        // chain: h = relu(pre + w1c*c); zc via 4 parallel accumulators
        float zc0 = b2c, zc1 = 0.f, zc2 = 0.f, zc3 = 0.f;
#pragma unroll
        for (int j = 0; j < HIDDEN; j += 4) {
          float h0 = fmaxf(fmaf(c, w1c[j + 0], pre[j + 0]), 0.f);
          float h1 = fmaxf(fmaf(c, w1c[j + 1], pre[j + 1]), 0.f);
          float h2 = fmaxf(fmaf(c, w1c[j + 2], pre[j + 2]), 0.f);
          float h3 = fmaxf(fmaf(c, w1c[j + 3], pre[j + 3]), 0.f);
          zc0 = fmaf(h0, w2c[j + 0], zc0);
          zc1 = fmaf(h1, w2c[j + 1], zc1);
          zc2 = fmaf(h2, w2c[j + 2], zc2);
          zc3 = fmaf(h3, w2c[j + 3], zc3);
        }
        c = sigmoid_pre((zc0 + zc1) + (zc2 + zc3));
      }
    }
  }

  // Main chunk: emit sum bits + advance carry.
  for (int g = 0; g < CHUNK / GRAN; ++g) {
    const int lb = l0 + g * GRAN;
    float4 a4[GRAN / 4], b4[GRAN / 4], y4[GRAN / 4];
#pragma unroll
    for (int q = 0; q < GRAN / 4; ++q) {
      a4[q] = *reinterpret_cast<const float4*>(r1 + lb + 4 * q);
      b4[q] = *reinterpret_cast<const float4*>(r2 + lb + 4 * q);
    }
    const float* af = reinterpret_cast<const float*>(a4);
    const float* bf = reinterpret_cast<const float*>(b4);
    float* yf = reinterpret_cast<float*>(y4);
#pragma unroll
    for (int u = 0; u < GRAN; ++u) {
      const float a = af[u];
      const float b = bf[u];
      float pre[HIDDEN];
#pragma unroll
      for (int j = 0; j < HIDDEN; ++j)
        pre[j] = fmaf(a, w1a[j], fmaf(b, w1b[j], bb1[j]));
      float zc0 = b2c, zc1 = 0.f, zc2 = 0.f, zc3 = 0.f;
      float zs0 = b2s, zs1 = 0.f;
#pragma unroll
      for (int j = 0; j < HIDDEN; j += 4) {
        float h0 = fmaxf(fmaf(c, w1c[j + 0], pre[j + 0]), 0.f);
        float h1 = fmaxf(fmaf(c, w1c[j + 1], pre[j + 1]), 0.f);
        float h2 = fmaxf(fmaf(c, w1c[j + 2], pre[j + 2]), 0.f);
        float h3 = fmaxf(fmaf(c, w1c[j + 3], pre[j + 3]), 0.f);
        zc0 = fmaf(h0, w2c[j + 0], zc0);
        zc1 = fmaf(h1, w2c[j + 1], zc1);
        zc2 = fmaf(h2, w2c[j + 2], zc2);
        zc3 = fmaf(h3, w2c[j + 3], zc3);
        // zs is off the carry chain; 2 accumulators is plenty
        zs0 = fmaf(h0, w2s[j + 0], fmaf(h1, w2s[j + 1], zs0));
        zs1 = fmaf(h2, w2s[j + 2], fmaf(h3, w2s[j + 3], zs1));
      }
      yf[u] = sigmoid_pre(zs0 + zs1);
      c = sigmoid_pre((zc0 + zc1) + (zc2 + zc3));
    }
#pragma unroll
    for (int q = 0; q < GRAN / 4; ++q) {
      *reinterpret_cast<float4*>(yo + lb + 4 * q) = y4[q];
    }
  }

  // Last chunk owns the final carry output.
  if (ci == NCHUNK - 1) {
    out[(size_t)Bn * Ln + row] = c;
  }
}

extern "C" void kernel_launch(void* const* d_in, const int* in_sizes, int n_in,
                              void* d_out, int out_size, void* d_ws,
                              size_t ws_size, hipStream_t stream) {
  const float* x1 = (const float*)d_in[0];
  const float* x2 = (const float*)d_in[1];
  const float* W1 = (const float*)d_in[2];
  const float* b1 = (const float*)d_in[3];
  const float* W2 = (const float*)d_in[4];
  const float* b2 = (const float*)d_in[5];
  float* out = (float*)d_out;

  dim3 grid(Bn / 64, NCHUNK);
  seq_adder_kernel<<<grid, 64, 0, stream>>>(x1, x2, W1, b1, W2, b2, out);
}

// Round 13
// 81.225 us; speedup vs baseline: 1.5703x; 1.0270x over previous
//
#include <hip/hip_runtime.h>

// SeqAdder: y[b,l], c_final[b] from a sequential per-digit MLP adder scan.
// Speculative chunked scan: carry recurrence is contracting; each chunk
// reconstructs its incoming carry with a WARM=48 warmup from c=0.5
// (absmax pinned at bf16 floor 1.95e-3 through R1-R4/R8/R9/R11/R12).
// R13 = R11's coalesced-LDS-staging idea with the three diagnosed bugs fixed:
//   - launch_bounds(64,2): 256-VGPR budget so the 32-VGPR staging tile
//     lives in registers (R11 spilled: WRITE_SIZE 75->246MB). R12 proved
//     the attribute itself is perf-neutral.
//   - STEP-MAJOR LDS layout lds[u*65 + r]: per-step reads lds[u*65+l] hit
//     banks (u+l)%32 -> conflict-free; writes are scalar b32 at immediate
//     offsets, ~2-way aliased (free, m136). R11's row-major LSTR=20 b128
//     reads were 8-way conflicted (1.43M conflicts).
//   - PIN_V(bb1/b2s/b2c): fmaf(b, w1b[SGPR], bb1[SGPR]) breaks the 1-SGPR
//     VOP3 rule -> compiler emitted ~16 v_movs/step. Pin to VGPR (ran in R10).
// Why staging at all: direct per-lane row streaming makes every
// global_load_dwordx4 a 64-distinct-line gather (4KB row stride). Traffic
// volume is ideal (FETCH 159MB) but VALUBusy is stuck at 56% with ~44%
// both-waves-stalled idle = gather serialization + latency. Cooperative
// tile load = 16 fully-consumed lines per instruction, issued a full
// compute-phase (~3400 cyc) ahead of use (T14 issue-early/write-late).

#define HIDDEN 16
constexpr int Bn = 4096;
constexpr int Ln = 4096;
constexpr int CHUNK = 128;           // steps written per thread
constexpr int WARM = 48;             // warmup steps (carry only)
constexpr int NCHUNK = Ln / CHUNK;   // 32
constexpr int GRAN = 16;             // steps per staged tile
constexpr int WG = WARM / GRAN;      // 3 warm tiles
constexpr int MG = CHUNK / GRAN;     // 8 main tiles
constexpr int LT = 65;               // LDS stride between steps (floats)

__device__ __forceinline__ float fast_exp2(float x) {
#if __has_builtin(__builtin_amdgcn_exp2f)
  return __builtin_amdgcn_exp2f(x);
#else
  return exp2f(x);
#endif
}
__device__ __forceinline__ float fast_rcp(float x) {
#if __has_builtin(__builtin_amdgcn_rcpf)
  return __builtin_amdgcn_rcpf(x);
#else
  return 1.0f / x;
#endif
}
// with z already scaled by -log2(e):  sigmoid = 1 / (1 + 2^z)
__device__ __forceinline__ float sigmoid_pre(float z) {
  return fast_rcp(1.0f + fast_exp2(z));
}

// Zero-instruction VGPR pin (forces allocation, emits nothing). Ran in R10.
#define PIN_V(x) asm("" : "+v"(x))

__global__ __launch_bounds__(64, 2) void seq_adder_kernel(
    const float* __restrict__ x1, const float* __restrict__ x2,
    const float* __restrict__ W1, const float* __restrict__ b1,
    const float* __restrict__ W2, const float* __restrict__ b2,
    float* __restrict__ out) {
  const int l = threadIdx.x;
  const int rowbase = blockIdx.x * 64;
  const int row = rowbase + l;
  const int ci = blockIdx.y;

  constexpr float NLOG2E = -1.4426950408889634f;

  // Wave-uniform weights -> SGPRs, except bb1/b2s/b2c pinned to VGPRs
  // (1-SGPR-operand rule: avoids ~16 v_movs per step).
  float w1a[HIDDEN], w1b[HIDDEN], w1c[HIDDEN], bb1[HIDDEN];
  float w2s[HIDDEN], w2c[HIDDEN];
#pragma unroll
  for (int j = 0; j < HIDDEN; ++j) {
    w1a[j] = W1[j];                       // W1[0, j] (multiplies a)
    w1b[j] = W1[HIDDEN + j];              // W1[1, j] (multiplies b)
    w1c[j] = W1[2 * HIDDEN + j];          // W1[2, j] (multiplies carry)
    bb1[j] = b1[j];
    PIN_V(bb1[j]);
    w2s[j] = W2[2 * j + 0] * NLOG2E;      // fold -log2(e) into layer 2
    w2c[j] = W2[2 * j + 1] * NLOG2E;
  }
  float b2s = b2[0] * NLOG2E, b2c = b2[1] * NLOG2E;
  PIN_V(b2s);
  PIN_V(b2c);

  // Step-major staging tiles: element (row r, step u) at lds[u*LT + r].
  __shared__ float lds_a[GRAN * LT];
  __shared__ float lds_b[GRAN * LT];

  float* __restrict__ yo = out + (size_t)row * Ln;

  // Cooperative-load geometry: load i covers rows 16i+(l>>2); each lane
  // loads 16B at steps (l&3)*4..+3 of its sub-row. 16 fully-consumed
  // cache lines per instruction (vs 64 partially-used for direct loads).
  const int cr = l >> 2;
  const int cc = (l & 3) * 4;      // starting step index this lane stages
  const float* ga = x1 + (size_t)(rowbase + cr) * Ln + cc;
  const float* gb = x2 + (size_t)(rowbase + cr) * Ln + cc;
  const int wbase = cc * LT + cr;  // LDS write base (compile-time offsets)

  const int l0 = ci * CHUNK;
  float c;

  float4 va[4], vb[4];  // staging regs, in flight across compute

#define LOAD_TILE(lb)                                                      \
  do {                                                                     \
    _Pragma("unroll") for (int i_ = 0; i_ < 4; ++i_) {                     \
      va[i_] = *reinterpret_cast<const float4*>(ga + (size_t)i_ * 16 * Ln  \
                                                + (lb));                   \
      vb[i_] = *reinterpret_cast<const float4*>(gb + (size_t)i_ * 16 * Ln  \
                                                + (lb));                   \
    }                                                                      \
  } while (0)

#define STORE_LDS()                                                        \
  do {                                                                     \
    _Pragma("unroll") for (int i_ = 0; i_ < 4; ++i_) {                     \
      lds_a[wbase + 0 * LT + 16 * i_] = va[i_].x;                          \
      lds_a[wbase + 1 * LT + 16 * i_] = va[i_].y;                          \
      lds_a[wbase + 2 * LT + 16 * i_] = va[i_].z;                          \
      lds_a[wbase + 3 * LT + 16 * i_] = va[i_].w;                          \
      lds_b[wbase + 0 * LT + 16 * i_] = vb[i_].x;                          \
      lds_b[wbase + 1 * LT + 16 * i_] = vb[i_].y;                          \
      lds_b[wbase + 2 * LT + 16 * i_] = vb[i_].z;                          \
      lds_b[wbase + 3 * LT + 16 * i_] = vb[i_].w;                          \
    }                                                                      \
  } while (0)

  if (ci == 0) {
    c = 0.0f;  // exact initial carry
    LOAD_TILE(l0);
  } else {
    c = 0.5f;  // neutral guess; contraction erases it over WARM steps
    const int w0 = l0 - WARM;
    LOAD_TILE(w0);
#pragma unroll 1
    for (int t = 0; t < WG; ++t) {
      STORE_LDS();                       // single-wave block: DS in-order,
      LOAD_TILE(w0 + (t + 1) * GRAN);    // no barrier needed. t==WG-1
                                         // loads main tile 0 (at l0).
#pragma unroll
      for (int u = 0; u < GRAN; ++u) {
        const float a = lds_a[u * LT + l];   // banks (u+l)%32: conflict-free
        const float b = lds_b[u * LT + l];
        float pre[HIDDEN];
#pragma unroll
        for (int j = 0; j < HIDDEN; ++j)
          pre[j] = fmaf(a, w1a[j], fmaf(b, w1b[j], bb1[j]));
        float zc0 = b2c, zc1 = 0.f, zc2 = 0.f, zc3 = 0.f;
#pragma unroll
        for (int j = 0; j < HIDDEN; j += 4) {
          float h0 = fmaxf(fmaf(c, w1c[j + 0], pre[j + 0]), 0.f);
          float h1 = fmaxf(fmaf(c, w1c[j + 1], pre[j + 1]), 0.f);
          float h2 = fmaxf(fmaf(c, w1c[j + 2], pre[j + 2]), 0.f);
          float h3 = fmaxf(fmaf(c, w1c[j + 3], pre[j + 3]), 0.f);
          zc0 = fmaf(h0, w2c[j + 0], zc0);
          zc1 = fmaf(h1, w2c[j + 1], zc1);
          zc2 = fmaf(h2, w2c[j + 2], zc2);
          zc3 = fmaf(h3, w2c[j + 3], zc3);
        }
        c = sigmoid_pre((zc0 + zc1) + (zc2 + zc3));
      }
    }
  }

  // Main: emit sum bits + advance carry.
#pragma unroll 1
  for (int g = 0; g < MG; ++g) {
    STORE_LDS();
    if (g + 1 < MG) LOAD_TILE(l0 + (g + 1) * GRAN);  // issue-early
    float y16[GRAN];
#pragma unroll
    for (int u = 0; u < GRAN; ++u) {
      const float a = lds_a[u * LT + l];
      const float b = lds_b[u * LT + l];
      float pre[HIDDEN];
#pragma unroll
      for (int j = 0; j < HIDDEN; ++j)
        pre[j] = fmaf(a, w1a[j], fmaf(b, w1b[j], bb1[j]));
      float zc0 = b2c, zc1 = 0.f, zc2 = 0.f, zc3 = 0.f;
      float zs0 = b2s, zs1 = 0.f;
#pragma unroll
      for (int j = 0; j < HIDDEN; j += 4) {
        float h0 = fmaxf(fmaf(c, w1c[j + 0], pre[j + 0]), 0.f);
        float h1 = fmaxf(fmaf(c, w1c[j + 1], pre[j + 1]), 0.f);
        float h2 = fmaxf(fmaf(c, w1c[j + 2], pre[j + 2]), 0.f);
        float h3 = fmaxf(fmaf(c, w1c[j + 3], pre[j + 3]), 0.f);
        zc0 = fmaf(h0, w2c[j + 0], zc0);
        zc1 = fmaf(h1, w2c[j + 1], zc1);
        zc2 = fmaf(h2, w2c[j + 2], zc2);
        zc3 = fmaf(h3, w2c[j + 3], zc3);
        // zs is off the carry chain; 2 accumulators is plenty
        zs0 = fmaf(h0, w2s[j + 0], fmaf(h1, w2s[j + 1], zs0));
        zs1 = fmaf(h2, w2s[j + 2], fmaf(h3, w2s[j + 3], zs1));
      }
      y16[u] = sigmoid_pre(zs0 + zs1);
      c = sigmoid_pre((zc0 + zc1) + (zc2 + zc3));
    }
#pragma unroll
    for (int q = 0; q < 4; ++q) {
      *reinterpret_cast<float4*>(yo + l0 + g * GRAN + 4 * q) =
          make_float4(y16[4 * q], y16[4 * q + 1], y16[4 * q + 2],
                      y16[4 * q + 3]);
    }
  }

  // Last chunk owns the final carry output.
  if (ci == NCHUNK - 1) {
    out[(size_t)Bn * Ln + row] = c;
  }
}

extern "C" void kernel_launch(void* const* d_in, const int* in_sizes, int n_in,
                              void* d_out, int out_size, void* d_ws,
                              size_t ws_size, hipStream_t stream) {
  const float* x1 = (const float*)d_in[0];
  const float* x2 = (const float*)d_in[1];
  const float* W1 = (const float*)d_in[2];
  const float* b1 = (const float*)d_in[3];
  const float* W2 = (const float*)d_in[4];
  const float* b2 = (const float*)d_in[5];
  float* out = (float*)d_out;

  dim3 grid(Bn / 64, NCHUNK);
  seq_adder_kernel<<<grid, 64, 0, stream>>>(x1, x2, W1, b1, W2, b2, out);
}